// Round 5
// baseline (380.767 us; speedup 1.0000x reference)
//
#include <hip/hip_runtime.h>
#include <math.h>

// Problem constants
#define T_ENC 50
#define T_DEC 60
#define HID   128
#define EMB   64
#define DIN   2
#define MT    16      // batch rows per block
#define NTHR  512     // 8 waves, 1 block/CU -> 2 waves/SIMD
#define HS    136     // shorts per h row (16B-aligned; 272B row stride -> A-frag
                      // b128 reads are 2-way bank aliased = free (m136))

typedef __attribute__((ext_vector_type(8))) short frag8;  // 8 bf16 (4 VGPRs)
typedef __attribute__((ext_vector_type(4))) float f32x4;  // 4 fp32 acc

__device__ __forceinline__ float fast_rcp(float x) { return __builtin_amdgcn_rcpf(x); }
__device__ __forceinline__ float sigm(float x) { return fast_rcp(1.f + __expf(-x)); }
__device__ __forceinline__ float tanh_fast(float x) { return fmaf(2.f, fast_rcp(1.f + __expf(-2.f * x)), -1.f); }

// NUMERICS LOCK (R13 post-mortem): only bitwise-preserving changes. Every FP
// op and its association order is frozen (R13's ulp-level reassociations ->
// absmax 0.756 fail vs 5.6e-3 threshold).

// R12: 16-lane sum on the VALU pipe (DPP row_ror) — same balanced tree as the
// xor butterfly: bitwise-identical sums; all 16 lanes end with the group sum.
__device__ __forceinline__ float reduce16_dpp(float x) {
    x += __int_as_float(__builtin_amdgcn_update_dpp(0, __float_as_int(x), 0x121, 0xF, 0xF, false)); // row_ror:1
    x += __int_as_float(__builtin_amdgcn_update_dpp(0, __float_as_int(x), 0x122, 0xF, 0xF, false)); // row_ror:2
    x += __int_as_float(__builtin_amdgcn_update_dpp(0, __float_as_int(x), 0x124, 0xF, 0xF, false)); // row_ror:4
    x += __int_as_float(__builtin_amdgcn_update_dpp(0, __float_as_int(x), 0x128, 0xF, 0xF, false)); // row_ror:8
    return x;
}

// Split 8 consecutive floats W[n][kb..kb+7] into hi/lo bf16 fragment registers.
__device__ __forceinline__ void load_wfrag(const float* __restrict__ wrow,
                                           frag8& Fhi, frag8& Flo) {
    union { unsigned short s[8]; frag8 f; } hi, lo;
#pragma unroll
    for (int j = 0; j < 8; ++j) {
        float x      = wrow[j];
        unsigned u   = __float_as_uint(x);
        unsigned uhi = u & 0xffff0000u;
        float    lof = x - __uint_as_float(uhi);   // exact remainder
        hi.s[j] = (unsigned short)(uhi >> 16);
        lo.s[j] = (unsigned short)(__float_as_uint(lof) >> 16);
    }
    Fhi = hi.f; Flo = lo.f;
}

__device__ __forceinline__ void split2(float x, unsigned short& hi, unsigned short& lo) {
    unsigned u   = __float_as_uint(x);
    unsigned uhi = u & 0xffff0000u;
    float    lof = x - __uint_as_float(uhi);
    hi = (unsigned short)(uhi >> 16);
    lo = (unsigned short)(__float_as_uint(lof) >> 16);
}

// Structure lock (R5-R11): one weight-resident 8-wave block per CU; per-step
// all-wave barriers required by the h cross-wave dependency.
// R16 sync restructure (evidence: R12/R14/R15 DS-pipe surgery moved <2% ->
// the stall is rendezvous cost, not DS):
//  (a) pass-2 MFMAs issued AFTER B1 — they now overlap the pred-sum phase
//      that used to sit in a dead B1->B1.5 window.
//  (b) B1.5 deleted. It was a full 8-wave rendezvous for a 1->7 hand-off.
//      Wave 0 issues its part_s reads right after B1 (latency hidden under
//      everyone's pass-2 issue), computes the SAME b2-first wi-ascending
//      sums (same bits), publishes part_f + a monotonic LDS flag (release);
//      consumers acquire-poll — usually already set. Barriers/step: 3 -> 2.
__global__ __launch_bounds__(NTHR, 2) void lstm_all(
    const float* __restrict__ history,  // (B, 50, 2)
    const float* __restrict__ W_emb,    // (64, 2)
    const float* __restrict__ b_emb,    // (64)
    const float* __restrict__ W_ih,     // (512, 64)
    const float* __restrict__ W_hh,     // (512, 128)
    const float* __restrict__ b_ih,     // (512)
    const float* __restrict__ b_hh,     // (512)
    const float* __restrict__ W1,       // (128, 128)
    const float* __restrict__ b1,       // (128)
    const float* __restrict__ w2,       // (2, 128)
    const float* __restrict__ b2,       // (2)
    float* __restrict__ out)            // (B, 60, 2)
{
    __shared__ __align__(16) unsigned short hhi[2][MT * HS];   // 8.7 KB
    __shared__ __align__(16) unsigned short hlo[2][MT * HS];   // 8.7 KB
    __shared__ float hist_s[MT * T_ENC * DIN];                 // 6.4 KB
    __shared__ float pred_buf[MT * T_DEC * DIN];               // 7.7 KB
    __shared__ __align__(16) float2 part_s[8][MT];             // 1 KB
    __shared__ __align__(8)  float part_f[MT][2];              // 128 B compact sums
    __shared__ float wemb_s[EMB * DIN];
    __shared__ float bemb_s[EMB];
    __shared__ int pflag;                                      // R16 pred-ready flag

    const int tid = threadIdx.x;
    const int L   = tid & 63;
    const int w   = tid >> 6;       // wave 0..7
    const int nc  = L & 15;
    const int kb0 = (L >> 4) * 8;   // A-frag k base
    const int m0c = (L >> 4) * 4;   // C-frag row base
    const int r0  = blockIdx.x * MT;
    const int jcol = w * 16 + nc;   // owned hidden unit / gate sub-column

    // ---- staging ----
    for (int i = tid; i < MT * T_ENC * DIN; i += NTHR)
        hist_s[i] = history[r0 * T_ENC * DIN + i];
    for (int i = tid; i < MT * HS; i += NTHR) {
        hhi[0][i] = 0; hlo[0][i] = 0;
        hhi[1][i] = 0; hlo[1][i] = 0;
    }
    if (tid < EMB * DIN) wemb_s[tid] = W_emb[tid];
    if (tid < EMB) bemb_s[tid] = b_emb[tid];
    if (tid == 0) pflag = 0;

    // ---- persistent weight fragments; __syncthreads() between groups caps
    //      landing-buffer pressure (R11: WRITE_SIZE 38 -> 14 MB) ----
    frag8 Bg[4][4][2];   // 128 VGPRs
#pragma unroll
    for (int g = 0; g < 4; ++g) {
#pragma unroll
        for (int ks = 0; ks < 4; ++ks) {
            int n = g * HID + jcol;
            load_wfrag(&W_hh[(size_t)n * HID + ks * 32 + kb0], Bg[g][ks][0], Bg[g][ks][1]);
        }
        __syncthreads();
    }
    frag8 Bw1[4][2];     // 32 VGPRs; wave owns u-tile w*16..+15
#pragma unroll
    for (int ks = 0; ks < 4; ++ks)
        load_wfrag(&W1[(size_t)jcol * HID + ks * 32 + kb0], Bw1[ks][0], Bw1[ks][1]);

    __syncthreads();   // staging visible

    // ---- folded rank-2 input map + biases for this lane's 4 gate columns ----
    float we0v[4], we1v[4], bs0v[4], bs1v[4];
#pragma unroll
    for (int g = 0; g < 4; ++g) {
        int n = g * HID + jcol;
        float s0 = 0.f, s1 = 0.f, sb = 0.f;
        const float* wr = &W_ih[(size_t)n * EMB];
#pragma unroll 4
        for (int e4 = 0; e4 < EMB / 4; ++e4) {
            float4 wv = *(const float4*)&wr[e4 * 4];
            int e = e4 * 4;
            s0 += wv.x * wemb_s[(e+0)*2] + wv.y * wemb_s[(e+1)*2]
                + wv.z * wemb_s[(e+2)*2] + wv.w * wemb_s[(e+3)*2];
            s1 += wv.x * wemb_s[(e+0)*2+1] + wv.y * wemb_s[(e+1)*2+1]
                + wv.z * wemb_s[(e+2)*2+1] + wv.w * wemb_s[(e+3)*2+1];
            sb += wv.x * bemb_s[e+0] + wv.y * bemb_s[e+1]
                + wv.z * bemb_s[e+2] + wv.w * bemb_s[e+3];
        }
        float b = b_ih[n] + b_hh[n];
        bs0v[g] = b;          // decoder step 0: prev is literal zeros
        bs1v[g] = b + sb;     // input went through embedding
        we0v[g] = s0; we1v[g] = s1;
    }
    const float b1v  = b1[jcol];
    const float w2v0 = w2[jcol];          // W2[0][u]
    const float w2v1 = w2[HID + jcol];    // W2[1][u]
    const float b2v0 = b2[0], b2v1 = b2[1];
    const int   fb   = nc * HS + kb0;     // A-frag base (shorts)
    float cst[4] = {0.f, 0.f, 0.f, 0.f};  // c state: rows m0c+r, unit jcol

    const unsigned short* Hh = hhi[0];
    const unsigned short* Hl = hlo[0];
    unsigned short* Nh = hhi[1];
    unsigned short* Nl = hlo[1];

    // =================== encoder: ONE barrier per step (dbuf) ===================
#pragma unroll 1
    for (int t = 0; t < T_ENC; ++t) {
        f32x4 acc[4];
        float q0[4], q1[4];
#pragma unroll
        for (int r = 0; r < 4; ++r) {
            float2 q = *(const float2*)&hist_s[(m0c + r) * (T_ENC * DIN) + t * DIN];
            q0[r] = q.x; q1[r] = q.y;
        }
#pragma unroll
        for (int g = 0; g < 4; ++g)
#pragma unroll
            for (int r = 0; r < 4; ++r)
                acc[g][r] = fmaf(q1[r], we1v[g], fmaf(q0[r], we0v[g], bs1v[g]));

#pragma unroll
        for (int ks = 0; ks < 4; ++ks) {
            frag8 Ahi = *(const frag8*)(Hh + fb + ks * 32);
            frag8 Alo = *(const frag8*)(Hl + fb + ks * 32);
#pragma unroll
            for (int g = 0; g < 4; ++g)
                acc[g] = __builtin_amdgcn_mfma_f32_16x16x32_bf16(Ahi, Bg[g][ks][1], acc[g], 0, 0, 0);
#pragma unroll
            for (int g = 0; g < 4; ++g)
                acc[g] = __builtin_amdgcn_mfma_f32_16x16x32_bf16(Alo, Bg[g][ks][0], acc[g], 0, 0, 0);
#pragma unroll
            for (int g = 0; g < 4; ++g)
                acc[g] = __builtin_amdgcn_mfma_f32_16x16x32_bf16(Ahi, Bg[g][ks][0], acc[g], 0, 0, 0);
        }

#pragma unroll
        for (int r = 0; r < 4; ++r) {
            float i_ = sigm(acc[0][r]);
            float f_ = sigm(acc[1][r]);
            float gv = tanh_fast(acc[2][r]);
            float o_ = sigm(acc[3][r]);
            cst[r] = fmaf(f_, cst[r], i_ * gv);
            float h = o_ * tanh_fast(cst[r]);
            unsigned short phi, plo;
            split2(h, phi, plo);
            Nh[(m0c + r) * HS + jcol] = phi;
            Nl[(m0c + r) * HS + jcol] = plo;
        }
        { const unsigned short* th = Hh; Hh = Nh; Nh = (unsigned short*)th;
          const unsigned short* tl = Hl; Hl = Nl; Nl = (unsigned short*)tl; }
        __syncthreads();
    }

    // =================== decoder step 0 (peeled: prev = zeros) ===================
    {
        f32x4 acc[4];
#pragma unroll
        for (int g = 0; g < 4; ++g)
            acc[g] = (f32x4){bs0v[g], bs0v[g], bs0v[g], bs0v[g]};
#pragma unroll
        for (int ks = 0; ks < 4; ++ks) {
            frag8 Ahi = *(const frag8*)(Hh + fb + ks * 32);
            frag8 Alo = *(const frag8*)(Hl + fb + ks * 32);
#pragma unroll
            for (int g = 0; g < 4; ++g)
                acc[g] = __builtin_amdgcn_mfma_f32_16x16x32_bf16(Ahi, Bg[g][ks][1], acc[g], 0, 0, 0);
#pragma unroll
            for (int g = 0; g < 4; ++g)
                acc[g] = __builtin_amdgcn_mfma_f32_16x16x32_bf16(Alo, Bg[g][ks][0], acc[g], 0, 0, 0);
#pragma unroll
            for (int g = 0; g < 4; ++g)
                acc[g] = __builtin_amdgcn_mfma_f32_16x16x32_bf16(Ahi, Bg[g][ks][0], acc[g], 0, 0, 0);
        }
#pragma unroll
        for (int r = 0; r < 4; ++r) {
            float i_ = sigm(acc[0][r]);
            float f_ = sigm(acc[1][r]);
            float gv = tanh_fast(acc[2][r]);
            float o_ = sigm(acc[3][r]);
            cst[r] = fmaf(f_, cst[r], i_ * gv);
            float h = o_ * tanh_fast(cst[r]);
            unsigned short phi, plo;
            split2(h, phi, plo);
            Nh[(m0c + r) * HS + jcol] = phi;
            Nl[(m0c + r) * HS + jcol] = plo;
        }
        { const unsigned short* th = Hh; Hh = Nh; Nh = (unsigned short*)th;
          const unsigned short* tl = Hl; Hl = Nl; Nl = (unsigned short*)tl; }
        __syncthreads();
    }

    // =================== decoder steps 1..59: restructured sync ===================
#pragma unroll 1
    for (int it = 1; it < T_DEC; ++it) {
        f32x4 acc[4];
        f32x4 hacc = (f32x4){b1v, b1v, b1v, b1v};
#pragma unroll
        for (int g = 0; g < 4; ++g)
            acc[g] = (f32x4){bs1v[g], bs1v[g], bs1v[g], bs1v[g]};

        // single LDS read of this step's A-frags (held across both passes, R12)
        frag8 Ah[4], Al[4];
#pragma unroll
        for (int ks = 0; ks < 4; ++ks) {
            Ah[ks] = *(const frag8*)(Hh + fb + ks * 32);
            Al[ks] = *(const frag8*)(Hl + fb + ks * 32);
        }

        // ---- pass 1: hacc (12) interleaved with the Ahi*Bhi gate product (16) ----
#pragma unroll
        for (int ks = 0; ks < 4; ++ks) {
            hacc = __builtin_amdgcn_mfma_f32_16x16x32_bf16(Ah[ks], Bw1[ks][1], hacc, 0, 0, 0);
            acc[0] = __builtin_amdgcn_mfma_f32_16x16x32_bf16(Ah[ks], Bg[0][ks][0], acc[0], 0, 0, 0);
            acc[1] = __builtin_amdgcn_mfma_f32_16x16x32_bf16(Ah[ks], Bg[1][ks][0], acc[1], 0, 0, 0);
            hacc = __builtin_amdgcn_mfma_f32_16x16x32_bf16(Al[ks], Bw1[ks][0], hacc, 0, 0, 0);
            acc[2] = __builtin_amdgcn_mfma_f32_16x16x32_bf16(Ah[ks], Bg[2][ks][0], acc[2], 0, 0, 0);
            acc[3] = __builtin_amdgcn_mfma_f32_16x16x32_bf16(Ah[ks], Bg[3][ks][0], acc[3], 0, 0, 0);
            hacc = __builtin_amdgcn_mfma_f32_16x16x32_bf16(Ah[ks], Bw1[ks][0], hacc, 0, 0, 0);
        }

        // hid=relu -> per-lane pred partials (waits on hacc only)
        float p0[4], p1[4];
#pragma unroll
        for (int r = 0; r < 4; ++r) {
            float hv = fmaxf(hacc[r], 0.f);
            p0[r] = hv * w2v0;
            p1[r] = hv * w2v1;
        }

        // 16-lane reduce on VALU (DPP)
#pragma unroll
        for (int r = 0; r < 4; ++r) {
            p0[r] = reduce16_dpp(p0[r]);
            p1[r] = reduce16_dpp(p1[r]);
        }
        // R14a: ONE lane per quad stores (identical values across the quad).
        if (nc == 0) {
#pragma unroll
            for (int r = 0; r < 4; ++r)
                part_s[w][m0c + r] = (float2){p0[r], p1[r]};
        }
        __syncthreads();   // B1: partials visible (arrives ~600 cyc earlier than R15)

        // R16: wave 0 issues its 8 part_s slot-reads NOW — latency hides under
        // everyone's pass-2 MFMA issue below. Lanes 32-63 mirror lanes 0-31
        // (broadcast reads, results unused).
        float rrd[8];
        if (w == 0) {
            const float* ps = (const float*)part_s;
            const int sl = (L & 31);
#pragma unroll
            for (int wi = 0; wi < 8; ++wi)
                rrd[wi] = ps[wi * 32 + sl];
        }

        // ---- pass 2: remaining gate products (32 MFMAs); frags from regs ----
#pragma unroll
        for (int ks = 0; ks < 4; ++ks) {
#pragma unroll
            for (int g = 0; g < 4; ++g)
                acc[g] = __builtin_amdgcn_mfma_f32_16x16x32_bf16(Ah[ks], Bg[g][ks][1], acc[g], 0, 0, 0);
#pragma unroll
            for (int g = 0; g < 4; ++g)
                acc[g] = __builtin_amdgcn_mfma_f32_16x16x32_bf16(Al[ks], Bg[g][ks][0], acc[g], 0, 0, 0);
        }

        // R16: wave 0 finishes the b2-first wi-ascending sums (same bits as
        // R15) and publishes part_f + flag. No B1.5 rendezvous.
        if (w == 0) {
            const int sl = (L & 31);
            const int mm = sl >> 1;
            const int dd = sl & 1;
            float s = dd ? b2v1 : b2v0;
#pragma unroll
            for (int wi = 0; wi < 8; ++wi)
                s += rrd[wi];
            if (L < 32) {
                ((float*)part_f)[sl] = s;
                pred_buf[(mm * T_DEC + (it - 1)) * DIN + dd] = s;
            }
            __threadfence_block();
            if (L == 0)
                __hip_atomic_store(&pflag, it, __ATOMIC_RELEASE, __HIP_MEMORY_SCOPE_WORKGROUP);
        }
        while (__hip_atomic_load(&pflag, __ATOMIC_ACQUIRE, __HIP_MEMORY_SCOPE_WORKGROUP) < it) {}

        // fold: 4 broadcast float2 reads per thread
#pragma unroll
        for (int r = 0; r < 4; ++r) {
            float2 pq = *(const float2*)&part_f[m0c + r][0];
#pragma unroll
            for (int g = 0; g < 4; ++g)
                acc[g][r] += fmaf(pq.y, we1v[g], pq.x * we0v[g]);
        }

        // pointwise -> h_it
#pragma unroll
        for (int r = 0; r < 4; ++r) {
            float i_ = sigm(acc[0][r]);
            float f_ = sigm(acc[1][r]);
            float gv = tanh_fast(acc[2][r]);
            float o_ = sigm(acc[3][r]);
            cst[r] = fmaf(f_, cst[r], i_ * gv);
            float h = o_ * tanh_fast(cst[r]);
            unsigned short phi, plo;
            split2(h, phi, plo);
            Nh[(m0c + r) * HS + jcol] = phi;
            Nl[(m0c + r) * HS + jcol] = plo;
        }
        { const unsigned short* th = Hh; Hh = Nh; Nh = (unsigned short*)th;
          const unsigned short* tl = Hl; Hl = Nl; Nl = (unsigned short*)tl; }
        __syncthreads();   // B2: new h visible (also orders part_s/part_f reuse)
    }

    // =================== tail: pred of the last decoder state ===================
    {
        f32x4 hacc = (f32x4){b1v, b1v, b1v, b1v};
#pragma unroll
        for (int ks = 0; ks < 4; ++ks) {
            frag8 Ahi = *(const frag8*)(Hh + fb + ks * 32);
            frag8 Alo = *(const frag8*)(Hl + fb + ks * 32);
            hacc = __builtin_amdgcn_mfma_f32_16x16x32_bf16(Ahi, Bw1[ks][1], hacc, 0, 0, 0);
            hacc = __builtin_amdgcn_mfma_f32_16x16x32_bf16(Alo, Bw1[ks][0], hacc, 0, 0, 0);
            hacc = __builtin_amdgcn_mfma_f32_16x16x32_bf16(Ahi, Bw1[ks][0], hacc, 0, 0, 0);
        }
        float p0[4], p1[4];
#pragma unroll
        for (int r = 0; r < 4; ++r) {
            float hv = fmaxf(hacc[r], 0.f);
            p0[r] = hv * w2v0;
            p1[r] = hv * w2v1;
        }
#pragma unroll
        for (int r = 0; r < 4; ++r) {
            p0[r] = reduce16_dpp(p0[r]);
            p1[r] = reduce16_dpp(p1[r]);
        }
        if (nc == 0) {
#pragma unroll
            for (int r = 0; r < 4; ++r)
                part_s[w][m0c + r] = (float2){p0[r], p1[r]};
        }
        __syncthreads();
        if (tid < 32) {
            const int mm = tid >> 1;
            const int dd = tid & 1;
            float s = dd ? b2v1 : b2v0;
#pragma unroll
            for (int wi = 0; wi < 8; ++wi)
                s += ((const float*)&part_s[wi][mm])[dd];
            pred_buf[(mm * T_DEC + (T_DEC - 1)) * DIN + dd] = s;
        }
        __syncthreads();
    }

    // ---- single coalesced flush of all preds ----
    for (int i = tid; i < MT * T_DEC * DIN; i += NTHR)
        out[(size_t)r0 * T_DEC * DIN + i] = pred_buf[i];
}

extern "C" void kernel_launch(void* const* d_in, const int* in_sizes, int n_in,
                              void* d_out, int out_size, void* d_ws, size_t ws_size,
                              hipStream_t stream) {
    const float* history = (const float*)d_in[0];
    const float* W_emb   = (const float*)d_in[1];
    const float* b_emb   = (const float*)d_in[2];
    const float* W_ih    = (const float*)d_in[3];
    const float* W_hh    = (const float*)d_in[4];
    const float* b_ih    = (const float*)d_in[5];
    const float* b_hh    = (const float*)d_in[6];
    const float* W1      = (const float*)d_in[7];
    const float* b1      = (const float*)d_in[8];
    const float* W2      = (const float*)d_in[9];
    const float* b2      = (const float*)d_in[10];
    float* out = (float*)d_out;
    (void)d_ws; (void)ws_size; (void)in_sizes; (void)n_in; (void)out_size;

    lstm_all<<<4096 / MT, NTHR, 0, stream>>>(history, W_emb, b_emb, W_ih, W_hh,
                                             b_ih, b_hh, W1, b1, W2, b2, out);
}

// Round 6
// 300.498 us; speedup vs baseline: 1.2671x; 1.2671x over previous
//
#include <hip/hip_runtime.h>
#include <math.h>

// Problem constants
#define T_ENC 50
#define T_DEC 60
#define HID   128
#define EMB   64
#define DIN   2
#define MT    16      // batch rows per block
#define NTHR  512     // 8 waves, 1 block/CU -> 2 waves/SIMD
#define HS    136     // shorts per h row (16B-aligned; 272B row stride -> A-frag
                      // b128 reads are 2-way bank aliased = free (m136))

typedef __attribute__((ext_vector_type(8))) short frag8;  // 8 bf16 (4 VGPRs)
typedef __attribute__((ext_vector_type(4))) float f32x4;  // 4 fp32 acc

__device__ __forceinline__ float fast_rcp(float x) { return __builtin_amdgcn_rcpf(x); }
__device__ __forceinline__ float sigm(float x) { return fast_rcp(1.f + __expf(-x)); }
__device__ __forceinline__ float tanh_fast(float x) { return fmaf(2.f, fast_rcp(1.f + __expf(-2.f * x)), -1.f); }

// NUMERICS LOCK (R13): only bitwise-preserving changes. Every FP op and its
// per-value association order is frozen (ulp-level reassociation -> 0.756 fail).
// SYNC LOCK (R16): s_barrier beats LDS flag+spin (threadfence drains, poll
// contention cost +77 us). Keep barriers.

// R12: 16-lane sum on the VALU pipe (DPP row_ror) — same balanced tree as the
// xor butterfly: bitwise-identical sums; all 16 lanes end with the group sum.
__device__ __forceinline__ float reduce16_dpp(float x) {
    x += __int_as_float(__builtin_amdgcn_update_dpp(0, __float_as_int(x), 0x121, 0xF, 0xF, false)); // row_ror:1
    x += __int_as_float(__builtin_amdgcn_update_dpp(0, __float_as_int(x), 0x122, 0xF, 0xF, false)); // row_ror:2
    x += __int_as_float(__builtin_amdgcn_update_dpp(0, __float_as_int(x), 0x124, 0xF, 0xF, false)); // row_ror:4
    x += __int_as_float(__builtin_amdgcn_update_dpp(0, __float_as_int(x), 0x128, 0xF, 0xF, false)); // row_ror:8
    return x;
}

// Split 8 consecutive floats W[n][kb..kb+7] into hi/lo bf16 fragment registers.
__device__ __forceinline__ void load_wfrag(const float* __restrict__ wrow,
                                           frag8& Fhi, frag8& Flo) {
    union { unsigned short s[8]; frag8 f; } hi, lo;
#pragma unroll
    for (int j = 0; j < 8; ++j) {
        float x      = wrow[j];
        unsigned u   = __float_as_uint(x);
        unsigned uhi = u & 0xffff0000u;
        float    lof = x - __uint_as_float(uhi);   // exact remainder
        hi.s[j] = (unsigned short)(uhi >> 16);
        lo.s[j] = (unsigned short)(__float_as_uint(lof) >> 16);
    }
    Fhi = hi.f; Flo = lo.f;
}

__device__ __forceinline__ void split2(float x, unsigned short& hi, unsigned short& lo) {
    unsigned u   = __float_as_uint(x);
    unsigned uhi = u & 0xffff0000u;
    float    lof = x - __uint_as_float(uhi);
    hi = (unsigned short)(uhi >> 16);
    lo = (unsigned short)(__float_as_uint(lof) >> 16);
}

// Structure lock (R5-R11): ~256 unified regs/wave (Bg 128 + Bw1 32 + working)
// pins occupancy at 8 waves/CU -> 2 waves/SIMD, lockstep. R17: with issue
// in-order, the tail's first acc use stalls on the FULL pass-2 drain when
// accumulators finish interleaved. Reorder MFMA bursts pair-major (acc0/1
// complete mid-burst), fold g-major, pointwise gate-major — pure inter-chain
// interleaving changes; every per-accumulator sequence and scalar op is
// unchanged => bitwise-identical output.
__global__ __launch_bounds__(NTHR, 2) void lstm_all(
    const float* __restrict__ history,  // (B, 50, 2)
    const float* __restrict__ W_emb,    // (64, 2)
    const float* __restrict__ b_emb,    // (64)
    const float* __restrict__ W_ih,     // (512, 64)
    const float* __restrict__ W_hh,     // (512, 128)
    const float* __restrict__ b_ih,     // (512)
    const float* __restrict__ b_hh,     // (512)
    const float* __restrict__ W1,       // (128, 128)
    const float* __restrict__ b1,       // (128)
    const float* __restrict__ w2,       // (2, 128)
    const float* __restrict__ b2,       // (2)
    float* __restrict__ out)            // (B, 60, 2)
{
    __shared__ __align__(16) unsigned short hhi[2][MT * HS];   // 8.7 KB
    __shared__ __align__(16) unsigned short hlo[2][MT * HS];   // 8.7 KB
    __shared__ float hist_s[MT * T_ENC * DIN];                 // 6.4 KB
    __shared__ float pred_buf[MT * T_DEC * DIN];               // 7.7 KB
    __shared__ __align__(16) float2 part_s[8][MT];             // 1 KB
    __shared__ __align__(8)  float part_f[MT][2];              // 128 B compact sums
    __shared__ float wemb_s[EMB * DIN];
    __shared__ float bemb_s[EMB];

    const int tid = threadIdx.x;
    const int L   = tid & 63;
    const int w   = tid >> 6;       // wave 0..7
    const int nc  = L & 15;
    const int kb0 = (L >> 4) * 8;   // A-frag k base
    const int m0c = (L >> 4) * 4;   // C-frag row base
    const int r0  = blockIdx.x * MT;
    const int jcol = w * 16 + nc;   // owned hidden unit / gate sub-column

    // ---- staging ----
    for (int i = tid; i < MT * T_ENC * DIN; i += NTHR)
        hist_s[i] = history[r0 * T_ENC * DIN + i];
    for (int i = tid; i < MT * HS; i += NTHR) {
        hhi[0][i] = 0; hlo[0][i] = 0;
        hhi[1][i] = 0; hlo[1][i] = 0;
    }
    if (tid < EMB * DIN) wemb_s[tid] = W_emb[tid];
    if (tid < EMB) bemb_s[tid] = b_emb[tid];

    // ---- persistent weight fragments; __syncthreads() between groups caps
    //      landing-buffer pressure (R11: WRITE_SIZE 38 -> 14 MB) ----
    frag8 Bg[4][4][2];   // 128 VGPRs
#pragma unroll
    for (int g = 0; g < 4; ++g) {
#pragma unroll
        for (int ks = 0; ks < 4; ++ks) {
            int n = g * HID + jcol;
            load_wfrag(&W_hh[(size_t)n * HID + ks * 32 + kb0], Bg[g][ks][0], Bg[g][ks][1]);
        }
        __syncthreads();
    }
    frag8 Bw1[4][2];     // 32 VGPRs; wave owns u-tile w*16..+15
#pragma unroll
    for (int ks = 0; ks < 4; ++ks)
        load_wfrag(&W1[(size_t)jcol * HID + ks * 32 + kb0], Bw1[ks][0], Bw1[ks][1]);

    __syncthreads();   // staging visible

    // ---- folded rank-2 input map + biases for this lane's 4 gate columns ----
    float we0v[4], we1v[4], bs0v[4], bs1v[4];
#pragma unroll
    for (int g = 0; g < 4; ++g) {
        int n = g * HID + jcol;
        float s0 = 0.f, s1 = 0.f, sb = 0.f;
        const float* wr = &W_ih[(size_t)n * EMB];
#pragma unroll 4
        for (int e4 = 0; e4 < EMB / 4; ++e4) {
            float4 wv = *(const float4*)&wr[e4 * 4];
            int e = e4 * 4;
            s0 += wv.x * wemb_s[(e+0)*2] + wv.y * wemb_s[(e+1)*2]
                + wv.z * wemb_s[(e+2)*2] + wv.w * wemb_s[(e+3)*2];
            s1 += wv.x * wemb_s[(e+0)*2+1] + wv.y * wemb_s[(e+1)*2+1]
                + wv.z * wemb_s[(e+2)*2+1] + wv.w * wemb_s[(e+3)*2+1];
            sb += wv.x * bemb_s[e+0] + wv.y * bemb_s[e+1]
                + wv.z * bemb_s[e+2] + wv.w * bemb_s[e+3];
        }
        float b = b_ih[n] + b_hh[n];
        bs0v[g] = b;          // decoder step 0: prev is literal zeros
        bs1v[g] = b + sb;     // input went through embedding
        we0v[g] = s0; we1v[g] = s1;
    }
    const float b1v  = b1[jcol];
    const float w2v0 = w2[jcol];          // W2[0][u]
    const float w2v1 = w2[HID + jcol];    // W2[1][u]
    const float b2v0 = b2[0], b2v1 = b2[1];
    const int   fb   = nc * HS + kb0;     // A-frag base (shorts)
    float cst[4] = {0.f, 0.f, 0.f, 0.f};  // c state: rows m0c+r, unit jcol

    const unsigned short* Hh = hhi[0];
    const unsigned short* Hl = hlo[0];
    unsigned short* Nh = hhi[1];
    unsigned short* Nl = hlo[1];

    // =================== encoder: ONE barrier per step (dbuf) ===================
#pragma unroll 1
    for (int t = 0; t < T_ENC; ++t) {
        f32x4 acc[4];
        float q0[4], q1[4];
#pragma unroll
        for (int r = 0; r < 4; ++r) {
            float2 q = *(const float2*)&hist_s[(m0c + r) * (T_ENC * DIN) + t * DIN];
            q0[r] = q.x; q1[r] = q.y;
        }
#pragma unroll
        for (int g = 0; g < 4; ++g)
#pragma unroll
            for (int r = 0; r < 4; ++r)
                acc[g][r] = fmaf(q1[r], we1v[g], fmaf(q0[r], we0v[g], bs1v[g]));

        // R17: pair-major burst — acc[p] per-acc order (ks asc: AhiBlo, AloBhi,
        // AhiBhi) identical to the old per-ks loop => same bits; acc0/1 finish
        // mid-burst so the gate-major pointwise overlaps acc2/3's drain.
#pragma unroll
        for (int p = 0; p < 4; p += 2) {
#pragma unroll
            for (int ks = 0; ks < 4; ++ks) {
                frag8 Ahi = *(const frag8*)(Hh + fb + ks * 32);
                frag8 Alo = *(const frag8*)(Hl + fb + ks * 32);
                acc[p]   = __builtin_amdgcn_mfma_f32_16x16x32_bf16(Ahi, Bg[p][ks][1],   acc[p],   0, 0, 0);
                acc[p+1] = __builtin_amdgcn_mfma_f32_16x16x32_bf16(Ahi, Bg[p+1][ks][1], acc[p+1], 0, 0, 0);
                acc[p]   = __builtin_amdgcn_mfma_f32_16x16x32_bf16(Alo, Bg[p][ks][0],   acc[p],   0, 0, 0);
                acc[p+1] = __builtin_amdgcn_mfma_f32_16x16x32_bf16(Alo, Bg[p+1][ks][0], acc[p+1], 0, 0, 0);
                acc[p]   = __builtin_amdgcn_mfma_f32_16x16x32_bf16(Ahi, Bg[p][ks][0],   acc[p],   0, 0, 0);
                acc[p+1] = __builtin_amdgcn_mfma_f32_16x16x32_bf16(Ahi, Bg[p+1][ks][0], acc[p+1], 0, 0, 0);
            }
        }

        // R17: gate-major pointwise (same scalar ops, reordered between
        // independent chains)
        float iv[4], fv[4], gv[4], ov[4];
#pragma unroll
        for (int r = 0; r < 4; ++r) iv[r] = sigm(acc[0][r]);
#pragma unroll
        for (int r = 0; r < 4; ++r) fv[r] = sigm(acc[1][r]);
#pragma unroll
        for (int r = 0; r < 4; ++r) gv[r] = tanh_fast(acc[2][r]);
#pragma unroll
        for (int r = 0; r < 4; ++r) ov[r] = sigm(acc[3][r]);
#pragma unroll
        for (int r = 0; r < 4; ++r) {
            cst[r] = fmaf(fv[r], cst[r], iv[r] * gv[r]);
            float h = ov[r] * tanh_fast(cst[r]);
            unsigned short phi, plo;
            split2(h, phi, plo);
            Nh[(m0c + r) * HS + jcol] = phi;
            Nl[(m0c + r) * HS + jcol] = plo;
        }
        { const unsigned short* th = Hh; Hh = Nh; Nh = (unsigned short*)th;
          const unsigned short* tl = Hl; Hl = Nl; Nl = (unsigned short*)tl; }
        __syncthreads();
    }

    // =================== decoder step 0 (peeled: prev = zeros) ===================
    {
        f32x4 acc[4];
#pragma unroll
        for (int g = 0; g < 4; ++g)
            acc[g] = (f32x4){bs0v[g], bs0v[g], bs0v[g], bs0v[g]};
#pragma unroll
        for (int p = 0; p < 4; p += 2) {
#pragma unroll
            for (int ks = 0; ks < 4; ++ks) {
                frag8 Ahi = *(const frag8*)(Hh + fb + ks * 32);
                frag8 Alo = *(const frag8*)(Hl + fb + ks * 32);
                acc[p]   = __builtin_amdgcn_mfma_f32_16x16x32_bf16(Ahi, Bg[p][ks][1],   acc[p],   0, 0, 0);
                acc[p+1] = __builtin_amdgcn_mfma_f32_16x16x32_bf16(Ahi, Bg[p+1][ks][1], acc[p+1], 0, 0, 0);
                acc[p]   = __builtin_amdgcn_mfma_f32_16x16x32_bf16(Alo, Bg[p][ks][0],   acc[p],   0, 0, 0);
                acc[p+1] = __builtin_amdgcn_mfma_f32_16x16x32_bf16(Alo, Bg[p+1][ks][0], acc[p+1], 0, 0, 0);
                acc[p]   = __builtin_amdgcn_mfma_f32_16x16x32_bf16(Ahi, Bg[p][ks][0],   acc[p],   0, 0, 0);
                acc[p+1] = __builtin_amdgcn_mfma_f32_16x16x32_bf16(Ahi, Bg[p+1][ks][0], acc[p+1], 0, 0, 0);
            }
        }
        float iv[4], fv[4], gv[4], ov[4];
#pragma unroll
        for (int r = 0; r < 4; ++r) iv[r] = sigm(acc[0][r]);
#pragma unroll
        for (int r = 0; r < 4; ++r) fv[r] = sigm(acc[1][r]);
#pragma unroll
        for (int r = 0; r < 4; ++r) gv[r] = tanh_fast(acc[2][r]);
#pragma unroll
        for (int r = 0; r < 4; ++r) ov[r] = sigm(acc[3][r]);
#pragma unroll
        for (int r = 0; r < 4; ++r) {
            cst[r] = fmaf(fv[r], cst[r], iv[r] * gv[r]);
            float h = ov[r] * tanh_fast(cst[r]);
            unsigned short phi, plo;
            split2(h, phi, plo);
            Nh[(m0c + r) * HS + jcol] = phi;
            Nl[(m0c + r) * HS + jcol] = plo;
        }
        { const unsigned short* th = Hh; Hh = Nh; Nh = (unsigned short*)th;
          const unsigned short* tl = Hl; Hl = Nl; Nl = (unsigned short*)tl; }
        __syncthreads();
    }

    // =================== decoder steps 1..59: two-pass burst ===================
#pragma unroll 1
    for (int it = 1; it < T_DEC; ++it) {
        f32x4 acc[4];
        f32x4 hacc = (f32x4){b1v, b1v, b1v, b1v};
#pragma unroll
        for (int g = 0; g < 4; ++g)
            acc[g] = (f32x4){bs1v[g], bs1v[g], bs1v[g], bs1v[g]};

        // single LDS read of this step's A-frags (held across both passes, R12)
        frag8 Ah[4], Al[4];
#pragma unroll
        for (int ks = 0; ks < 4; ++ks) {
            Ah[ks] = *(const frag8*)(Hh + fb + ks * 32);
            Al[ks] = *(const frag8*)(Hl + fb + ks * 32);
        }

        // ---- pass 1: hacc (12) interleaved with the Ahi*Bhi gate product (16) ----
#pragma unroll
        for (int ks = 0; ks < 4; ++ks) {
            hacc = __builtin_amdgcn_mfma_f32_16x16x32_bf16(Ah[ks], Bw1[ks][1], hacc, 0, 0, 0);
            acc[0] = __builtin_amdgcn_mfma_f32_16x16x32_bf16(Ah[ks], Bg[0][ks][0], acc[0], 0, 0, 0);
            acc[1] = __builtin_amdgcn_mfma_f32_16x16x32_bf16(Ah[ks], Bg[1][ks][0], acc[1], 0, 0, 0);
            hacc = __builtin_amdgcn_mfma_f32_16x16x32_bf16(Al[ks], Bw1[ks][0], hacc, 0, 0, 0);
            acc[2] = __builtin_amdgcn_mfma_f32_16x16x32_bf16(Ah[ks], Bg[2][ks][0], acc[2], 0, 0, 0);
            acc[3] = __builtin_amdgcn_mfma_f32_16x16x32_bf16(Ah[ks], Bg[3][ks][0], acc[3], 0, 0, 0);
            hacc = __builtin_amdgcn_mfma_f32_16x16x32_bf16(Ah[ks], Bw1[ks][0], hacc, 0, 0, 0);
        }

        // hid=relu -> per-lane pred partials (waits on hacc only)
        float p0[4], p1[4];
#pragma unroll
        for (int r = 0; r < 4; ++r) {
            float hv = fmaxf(hacc[r], 0.f);
            p0[r] = hv * w2v0;
            p1[r] = hv * w2v1;
        }

        // ---- pass 2 (R17 pair-major): per-acc order (ks asc: AhiBlo, AloBhi)
        //      identical to the old per-ks loop => same bits; acc0/1 complete
        //      mid-drain so the post-B1.5 fold/pointwise start earlier.
#pragma unroll
        for (int p = 0; p < 4; p += 2) {
#pragma unroll
            for (int ks = 0; ks < 4; ++ks) {
                acc[p]   = __builtin_amdgcn_mfma_f32_16x16x32_bf16(Ah[ks], Bg[p][ks][1],   acc[p],   0, 0, 0);
                acc[p+1] = __builtin_amdgcn_mfma_f32_16x16x32_bf16(Ah[ks], Bg[p+1][ks][1], acc[p+1], 0, 0, 0);
                acc[p]   = __builtin_amdgcn_mfma_f32_16x16x32_bf16(Al[ks], Bg[p][ks][0],   acc[p],   0, 0, 0);
                acc[p+1] = __builtin_amdgcn_mfma_f32_16x16x32_bf16(Al[ks], Bg[p+1][ks][0], acc[p+1], 0, 0, 0);
            }
        }

        // 16-lane reduce on VALU (DPP), overlapping the gate-MFMA drain
#pragma unroll
        for (int r = 0; r < 4; ++r) {
            p0[r] = reduce16_dpp(p0[r]);
            p1[r] = reduce16_dpp(p1[r]);
        }
        // R14a: ONE lane per quad stores (identical values across the quad).
        if (nc == 0) {
#pragma unroll
            for (int r = 0; r < 4; ++r)
                part_s[w][m0c + r] = (float2){p0[r], p1[r]};
        }
        __syncthreads();   // B1: partials visible — gate MFMAs still draining

        // R15 phase 1: wave 0 lanes 0..31 each own one (row,dim) slot; b2-first
        // wi-ascending adds => bitwise-identical sums.
        if (tid < 32) {
            const int mm = tid >> 1;
            const int dd = tid & 1;
            float s = dd ? b2v1 : b2v0;
#pragma unroll
            for (int wi = 0; wi < 8; ++wi)
                s += ((const float*)&part_s[wi][mm])[dd];
            part_f[mm][dd] = s;
            pred_buf[(mm * T_DEC + (it - 1)) * DIN + dd] = s;
        }
        __syncthreads();   // B1.5: compact pred sums visible

        // R17: fold g-major (pq preloaded) — acc[0] folds don't wait acc[3]
        float2 pqv[4];
#pragma unroll
        for (int r = 0; r < 4; ++r)
            pqv[r] = *(const float2*)&part_f[m0c + r][0];
#pragma unroll
        for (int g = 0; g < 4; ++g)
#pragma unroll
            for (int r = 0; r < 4; ++r)
                acc[g][r] += fmaf(pqv[r].y, we1v[g], pqv[r].x * we0v[g]);

        // R17: gate-major pointwise
        float iv[4], fv[4], gv[4], ov[4];
#pragma unroll
        for (int r = 0; r < 4; ++r) iv[r] = sigm(acc[0][r]);
#pragma unroll
        for (int r = 0; r < 4; ++r) fv[r] = sigm(acc[1][r]);
#pragma unroll
        for (int r = 0; r < 4; ++r) gv[r] = tanh_fast(acc[2][r]);
#pragma unroll
        for (int r = 0; r < 4; ++r) ov[r] = sigm(acc[3][r]);
#pragma unroll
        for (int r = 0; r < 4; ++r) {
            cst[r] = fmaf(fv[r], cst[r], iv[r] * gv[r]);
            float h = ov[r] * tanh_fast(cst[r]);
            unsigned short phi, plo;
            split2(h, phi, plo);
            Nh[(m0c + r) * HS + jcol] = phi;
            Nl[(m0c + r) * HS + jcol] = plo;
        }
        { const unsigned short* th = Hh; Hh = Nh; Nh = (unsigned short*)th;
          const unsigned short* tl = Hl; Hl = Nl; Nl = (unsigned short*)tl; }
        __syncthreads();   // B2: new h visible
    }

    // =================== tail: pred of the last decoder state ===================
    {
        f32x4 hacc = (f32x4){b1v, b1v, b1v, b1v};
#pragma unroll
        for (int ks = 0; ks < 4; ++ks) {
            frag8 Ahi = *(const frag8*)(Hh + fb + ks * 32);
            frag8 Alo = *(const frag8*)(Hl + fb + ks * 32);
            hacc = __builtin_amdgcn_mfma_f32_16x16x32_bf16(Ahi, Bw1[ks][1], hacc, 0, 0, 0);
            hacc = __builtin_amdgcn_mfma_f32_16x16x32_bf16(Alo, Bw1[ks][0], hacc, 0, 0, 0);
            hacc = __builtin_amdgcn_mfma_f32_16x16x32_bf16(Ahi, Bw1[ks][0], hacc, 0, 0, 0);
        }
        float p0[4], p1[4];
#pragma unroll
        for (int r = 0; r < 4; ++r) {
            float hv = fmaxf(hacc[r], 0.f);
            p0[r] = hv * w2v0;
            p1[r] = hv * w2v1;
        }
#pragma unroll
        for (int r = 0; r < 4; ++r) {
            p0[r] = reduce16_dpp(p0[r]);
            p1[r] = reduce16_dpp(p1[r]);
        }
        if (nc == 0) {
#pragma unroll
            for (int r = 0; r < 4; ++r)
                part_s[w][m0c + r] = (float2){p0[r], p1[r]};
        }
        __syncthreads();
        if (tid < 32) {
            const int mm = tid >> 1;
            const int dd = tid & 1;
            float s = dd ? b2v1 : b2v0;
#pragma unroll
            for (int wi = 0; wi < 8; ++wi)
                s += ((const float*)&part_s[wi][mm])[dd];
            pred_buf[(mm * T_DEC + (T_DEC - 1)) * DIN + dd] = s;
        }
        __syncthreads();
    }

    // ---- single coalesced flush of all preds ----
    for (int i = tid; i < MT * T_DEC * DIN; i += NTHR)
        out[(size_t)r0 * T_DEC * DIN + i] = pred_buf[i];
}

extern "C" void kernel_launch(void* const* d_in, const int* in_sizes, int n_in,
                              void* d_out, int out_size, void* d_ws, size_t ws_size,
                              hipStream_t stream) {
    const float* history = (const float*)d_in[0];
    const float* W_emb   = (const float*)d_in[1];
    const float* b_emb   = (const float*)d_in[2];
    const float* W_ih    = (const float*)d_in[3];
    const float* W_hh    = (const float*)d_in[4];
    const float* b_ih    = (const float*)d_in[5];
    const float* b_hh    = (const float*)d_in[6];
    const float* W1      = (const float*)d_in[7];
    const float* b1      = (const float*)d_in[8];
    const float* W2      = (const float*)d_in[9];
    const float* b2      = (const float*)d_in[10];
    float* out = (float*)d_out;
    (void)d_ws; (void)ws_size; (void)in_sizes; (void)n_in; (void)out_size;

    lstm_all<<<4096 / MT, NTHR, 0, stream>>>(history, W_emb, b_emb, W_ih, W_hh,
                                             b_ih, b_hh, W1, b1, W2, b2, out);
}